// Round 1
// baseline (7695.582 us; speedup 1.0000x reference)
//
#include <hip/hip_runtime.h>
#include <stdint.h>

// Binarized CNN (XNOR-net style), 7 layers, input (64,3,256,256).
// Key insight: all activations after layer 0 are EXACTLY ternary {-1,0,+1}
// (integer conv results clipped by hardtanh), so layers 1..6 are exact int8
// integer arithmetic. Layer 0 is the only fp-sensitive part: accumulate in
// double so the sign (taken after maxpool) matches a float64 reference.
//
// Buffers ping-pong in d_ws as int8:
//   A @ 0         (max 58,003,456 B  : L4 output 64x64x119x119)
//   B @ 58003712  (max 29,984,768 B  : L3 output 64x32x121x121)

// ---------------- Layer 0: conv(raw fp32, sign(w)) -> maxpool2 -> sign -> int8
__global__ __launch_bounds__(256) void conv0_pool_sign(
    const float* __restrict__ x, const float* __restrict__ w,
    int8_t* __restrict__ out)
{
    __shared__ float ws[108];  // sign(w0), (4,3,3,3)
    const int t = threadIdx.x;
    if (t < 108) {
        float v = w[t];
        ws[t] = (v > 0.f) ? 1.f : ((v < 0.f) ? -1.f : 0.f);
    }
    __syncthreads();
    const int idx = blockIdx.x * 256 + t;   // exact: 64*4*127*127 = 16129*256
    const int px = idx % 127;
    const int py = (idx / 127) % 127;
    const int co = (idx / (127 * 127)) % 4;
    const int n  = idx / (127 * 127 * 4);

    double a00 = 0.0, a01 = 0.0, a10 = 0.0, a11 = 0.0;
    const float* wsc = &ws[co * 27];
    for (int ci = 0; ci < 3; ++ci) {
        float patch[4][4];
        const float* xp = x + (((size_t)n * 3 + ci) * 256 + 2 * py) * 256 + 2 * px;
        #pragma unroll
        for (int r = 0; r < 4; ++r)
            #pragma unroll
            for (int c = 0; c < 4; ++c)
                patch[r][c] = xp[r * 256 + c];
        #pragma unroll
        for (int ky = 0; ky < 3; ++ky)
            #pragma unroll
            for (int kx = 0; kx < 3; ++kx) {
                const double wv = (double)wsc[ci * 9 + ky * 3 + kx];
                a00 += (double)patch[ky][kx]         * wv;
                a01 += (double)patch[ky][kx + 1]     * wv;
                a10 += (double)patch[ky + 1][kx]     * wv;
                a11 += (double)patch[ky + 1][kx + 1] * wv;
            }
    }
    const double m = fmax(fmax(a00, a01), fmax(a10, a11));
    out[idx] = (m > 0.0) ? (int8_t)1 : ((m < 0.0) ? (int8_t)(-1) : (int8_t)0);
}

// ---------------- Layers 1..6: ternary int8 conv, clip to [-1,1]
// grid = (cout, tiles, 64), block = 256 (16x16 output tile), weights in LDS.
template <int CIN, bool FOUT>
__global__ __launch_bounds__(256) void conv_tern(
    const int8_t* __restrict__ x, const float* __restrict__ w,
    void* __restrict__ outp, int cout, int H, int Ho)
{
    __shared__ int8_t ws[CIN * 9];
    const int t  = threadIdx.x;
    const int co = blockIdx.x;
    const int n  = blockIdx.z;
    for (int i = t; i < CIN * 9; i += 256) {
        float v = w[(size_t)co * CIN * 9 + i];
        ws[i] = (v > 0.f) ? (int8_t)1 : ((v < 0.f) ? (int8_t)(-1) : (int8_t)0);
    }
    __syncthreads();

    const int Wo = Ho, W = H;  // square images
    const int tiles_x = (Wo + 15) >> 4;
    const int px = (blockIdx.y % tiles_x) * 16 + (t & 15);
    const int py = (blockIdx.y / tiles_x) * 16 + (t >> 4);
    if (px >= Wo || py >= Ho) return;

    const int8_t* xb = x + (size_t)n * CIN * H * W + (size_t)py * W + px;
    int acc = 0;
    #pragma unroll 4
    for (int ci = 0; ci < CIN; ++ci) {
        const int8_t* xc = xb + (size_t)ci * H * W;
        #pragma unroll
        for (int ky = 0; ky < 3; ++ky) {
            const int8_t* row = xc + ky * W;
            const int w0 = ws[ci * 9 + ky * 3 + 0];
            const int w1 = ws[ci * 9 + ky * 3 + 1];
            const int w2 = ws[ci * 9 + ky * 3 + 2];
            acc += w0 * (int)row[0] + w1 * (int)row[1] + w2 * (int)row[2];
        }
    }
    acc = acc > 1 ? 1 : (acc < -1 ? -1 : acc);
    const size_t o = ((size_t)(n * cout + co) * Ho + py) * Wo + px;
    if (FOUT) ((float*)outp)[o] = (float)acc;
    else      ((int8_t*)outp)[o] = (int8_t)acc;
}

extern "C" void kernel_launch(void* const* d_in, const int* in_sizes, int n_in,
                              void* d_out, int out_size, void* d_ws, size_t ws_size,
                              hipStream_t stream) {
    const float* x  = (const float*)d_in[0];
    const float* w0 = (const float*)d_in[1];
    const float* w1 = (const float*)d_in[2];
    const float* w2 = (const float*)d_in[3];
    const float* w3 = (const float*)d_in[4];
    const float* w4 = (const float*)d_in[5];
    const float* w5 = (const float*)d_in[6];
    const float* w6 = (const float*)d_in[7];

    int8_t* A = (int8_t*)d_ws;
    int8_t* B = A + 58003712;

    // L0: (64,3,256,256) -> signs (64,4,127,127)
    conv0_pool_sign<<<16129, 256, 0, stream>>>(x, w0, A);

    auto tiles = [](int Ho) { int tx = (Ho + 15) / 16; return tx * tx; };

    // L1: 4->8,   in 127 -> out 125
    conv_tern<4,  false><<<dim3(8,  tiles(125), 64), 256, 0, stream>>>(A, w1, B, 8,  127, 125);
    // L2: 8->16,  125 -> 123
    conv_tern<8,  false><<<dim3(16, tiles(123), 64), 256, 0, stream>>>(B, w2, A, 16, 125, 123);
    // L3: 16->32, 123 -> 121
    conv_tern<16, false><<<dim3(32, tiles(121), 64), 256, 0, stream>>>(A, w3, B, 32, 123, 121);
    // L4: 32->64, 121 -> 119
    conv_tern<32, false><<<dim3(64, tiles(119), 64), 256, 0, stream>>>(B, w4, A, 64, 121, 119);
    // L5: 64->32, 119 -> 117
    conv_tern<64, false><<<dim3(32, tiles(117), 64), 256, 0, stream>>>(A, w5, B, 32, 119, 117);
    // L6: 32->2,  117 -> 115, float out to d_out
    conv_tern<32, true ><<<dim3(2,  tiles(115), 64), 256, 0, stream>>>(B, w6, d_out, 2, 117, 115);
}

// Round 2
// 766.294 us; speedup vs baseline: 10.0426x; 10.0426x over previous
//
#include <hip/hip_runtime.h>
#include <stdint.h>

// Ternary CNN. Layers 1..6 are exact int8 ternary convs done with v_dot4_i32_i8
// along the width axis: window (in[px..px+3]) dot (w0,w1,w2,0) = one 3-tap conv.
// Each thread: 4 horizontal outputs x 2 rows x CO couts from dword loads.
// Intermediate buffers have row stride padded to a multiple of 4 so dword
// loads are aligned. Layer 0 stays fp64-accumulated (sign after maxpool must
// match the float64 reference exactly).
//
// Workspace layout (int8):
//  A @ 0        : L0 out (64,4,127,s128)=4.16MB ; L2 out (64,16,123,s124)=15.6MB ;
//                 L4 out (64,64,119,s120)=58.49MB   (A size 58,491,136)
//  B @ 58491136 : L1 out (64,8,125,s128)=8.19MB ; L3 out (64,32,121,s124)=30.73MB ;
//                 L5 out (64,32,117,s120)=28.75MB
// Total ~89.2MB. Horizontal 4B over-reads land inside the workspace.

#define DEVINL __device__ __forceinline__

DEVINL uint32_t alignb(uint32_t hi, uint32_t lo, int k) {
#if __has_builtin(__builtin_amdgcn_alignbyte)
    return __builtin_amdgcn_alignbyte(hi, lo, (uint32_t)k);
#else
    return (uint32_t)(((((uint64_t)hi) << 32) | (uint64_t)lo) >> (8 * k));
#endif
}

DEVINL int dot4(uint32_t a, uint32_t b, int c) {
#if __has_builtin(__builtin_amdgcn_sdot4)
    return __builtin_amdgcn_sdot4((int)a, (int)b, c, false);
#else
    #pragma unroll
    for (int i = 0; i < 4; ++i)
        c += (int)(int8_t)(a >> (8 * i)) * (int)(int8_t)(b >> (8 * i));
    return c;
#endif
}

// ---------------- Layer 0: conv(raw fp32, sign(w)) -> maxpool2 -> sign -> int8
__global__ __launch_bounds__(256) void conv0_pool_sign(
    const float* __restrict__ x, const float* __restrict__ w,
    int8_t* __restrict__ out)
{
    __shared__ float ws[108];  // sign(w0), (4,3,3,3)
    const int t = threadIdx.x;
    if (t < 108) {
        float v = w[t];
        ws[t] = (v > 0.f) ? 1.f : ((v < 0.f) ? -1.f : 0.f);
    }
    __syncthreads();
    const int idx = blockIdx.x * 256 + t;   // exact: 64*4*127*127 = 16129*256
    const int px = idx % 127;
    const int py = (idx / 127) % 127;
    const int co = (idx / (127 * 127)) % 4;
    const int n  = idx / (127 * 127 * 4);

    double a00 = 0.0, a01 = 0.0, a10 = 0.0, a11 = 0.0;
    const float* wsc = &ws[co * 27];
    for (int ci = 0; ci < 3; ++ci) {
        float patch[4][4];
        const float* xp = x + (((size_t)n * 3 + ci) * 256 + 2 * py) * 256 + 2 * px;
        #pragma unroll
        for (int r = 0; r < 4; ++r)
            #pragma unroll
            for (int c = 0; c < 4; ++c)
                patch[r][c] = xp[r * 256 + c];
        #pragma unroll
        for (int ky = 0; ky < 3; ++ky)
            #pragma unroll
            for (int kx = 0; kx < 3; ++kx) {
                const double wv = (double)wsc[ci * 9 + ky * 3 + kx];
                a00 += (double)patch[ky][kx]         * wv;
                a01 += (double)patch[ky][kx + 1]     * wv;
                a10 += (double)patch[ky + 1][kx]     * wv;
                a11 += (double)patch[ky + 1][kx + 1] * wv;
            }
    }
    const double m = fmax(fmax(a00, a01), fmax(a10, a11));
    // padded output: stride 128
    const size_t o = (((size_t)n * 4 + co) * 127 + py) * 128 + px;
    out[o] = (m > 0.0) ? (int8_t)1 : ((m < 0.0) ? (int8_t)(-1) : (int8_t)0);
}

// ---------------- Layers 1..6: ternary conv via sdot4.
// Block = 256 threads = 16 px-groups (4 px each) x 16 y-groups (2 rows each)
// -> 64 x 32 output tile, CO couts per block.
// in: (N,CIN,W,WS) int8 ternary; out: (N,cout,Wo,WSo) int8 (or float, unpadded).
template <int CIN, int CO, bool FOUT>
__global__ __launch_bounds__(256) void conv_dot(
    const int8_t* __restrict__ in, const float* __restrict__ w,
    void* __restrict__ outp, int cout, int W, int WS, int Wo, int WSo)
{
    __shared__ uint32_t pw[CIN * 3 * CO];  // [(ci*3+ky)*CO + co] = packed (w0,w1,w2,0)
    const int t  = threadIdx.x;
    const int cg = blockIdx.x;
    const int n  = blockIdx.z;
    for (int i = t; i < CIN * 3 * CO; i += 256) {
        const int co = i % CO;
        const int r  = i / CO;
        const int ky = r % 3;
        const int ci = r / 3;
        const float* wp = w + (((size_t)(cg * CO + co) * CIN + ci) * 9 + ky * 3);
        uint32_t u = 0;
        #pragma unroll
        for (int k = 0; k < 3; ++k) {
            float v = wp[k];
            int s = (v > 0.f) ? 1 : ((v < 0.f) ? -1 : 0);
            u |= ((uint32_t)(uint8_t)(int8_t)s) << (8 * k);
        }
        pw[i] = u;
    }
    __syncthreads();

    const int tiles_x = (Wo + 63) >> 6;
    const int bx = blockIdx.y % tiles_x;
    const int by = blockIdx.y / tiles_x;
    const int px = bx * 64 + (t & 15) * 4;
    const int py = by * 32 + (t >> 4) * 2;
    if (px >= Wo || py >= Wo) return;

    const size_t ch = (size_t)W * WS;
    const int8_t* p0 = in + (size_t)n * CIN * ch + (size_t)py * WS + px;
    const int r3off = (py + 3 < W) ? 3 * WS : 0;  // guard last-row over-read

    int acc[CO][2][4];
    #pragma unroll
    for (int co = 0; co < CO; ++co)
        #pragma unroll
        for (int rr = 0; rr < 2; ++rr)
            #pragma unroll
            for (int j = 0; j < 4; ++j) acc[co][rr][j] = 0;

    #pragma unroll 2
    for (int ci = 0; ci < CIN; ++ci) {
        const int8_t* p = p0 + (size_t)ci * ch;
        uint32_t da[4], db[4];
        {
            const uint32_t* q0 = (const uint32_t*)p;
            const uint32_t* q1 = (const uint32_t*)(p + WS);
            const uint32_t* q2 = (const uint32_t*)(p + 2 * WS);
            const uint32_t* q3 = (const uint32_t*)(p + r3off);
            da[0] = q0[0]; db[0] = q0[1];
            da[1] = q1[0]; db[1] = q1[1];
            da[2] = q2[0]; db[2] = q2[1];
            da[3] = q3[0]; db[3] = q3[1];
        }
        uint32_t wv[3][CO];
        #pragma unroll
        for (int ky = 0; ky < 3; ++ky)
            #pragma unroll
            for (int co = 0; co < CO; ++co)
                wv[ky][co] = pw[(ci * 3 + ky) * CO + co];

        #pragma unroll
        for (int r = 0; r < 4; ++r) {
            uint32_t sw[4];
            sw[0] = da[r];
            sw[1] = alignb(db[r], da[r], 1);
            sw[2] = alignb(db[r], da[r], 2);
            sw[3] = alignb(db[r], da[r], 3);
            #pragma unroll
            for (int co = 0; co < CO; ++co) {
                if (r < 3) {
                    #pragma unroll
                    for (int j = 0; j < 4; ++j)
                        acc[co][0][j] = dot4(sw[j], wv[r][co], acc[co][0][j]);
                }
                if (r >= 1) {
                    #pragma unroll
                    for (int j = 0; j < 4; ++j)
                        acc[co][1][j] = dot4(sw[j], wv[r - 1][co], acc[co][1][j]);
                }
            }
        }
    }

    #pragma unroll
    for (int co = 0; co < CO; ++co) {
        const int c = cg * CO + co;
        #pragma unroll
        for (int rr = 0; rr < 2; ++rr) {
            const int y = py + rr;
            if (y >= Wo) continue;
            if (FOUT) {
                float* o = (float*)outp + ((size_t)n * cout + c) * ((size_t)Wo * Wo)
                         + (size_t)y * Wo + px;
                #pragma unroll
                for (int j = 0; j < 4; ++j)
                    if (px + j < Wo) {
                        int a = acc[co][rr][j];
                        a = a > 1 ? 1 : (a < -1 ? -1 : a);
                        o[j] = (float)a;
                    }
            } else {
                int8_t* o = (int8_t*)outp + ((size_t)n * cout + c) * ((size_t)Wo * WSo)
                          + (size_t)y * WSo + px;
                if (px + 4 <= Wo) {
                    uint32_t u = 0;
                    #pragma unroll
                    for (int j = 0; j < 4; ++j) {
                        int a = acc[co][rr][j];
                        a = a > 1 ? 1 : (a < -1 ? -1 : a);
                        u |= ((uint32_t)(uint8_t)(int8_t)a) << (8 * j);
                    }
                    *(uint32_t*)o = u;
                } else {
                    #pragma unroll
                    for (int j = 0; j < 4; ++j)
                        if (px + j < Wo) {
                            int a = acc[co][rr][j];
                            a = a > 1 ? 1 : (a < -1 ? -1 : a);
                            o[j] = (int8_t)a;
                        }
                }
            }
        }
    }
}

extern "C" void kernel_launch(void* const* d_in, const int* in_sizes, int n_in,
                              void* d_out, int out_size, void* d_ws, size_t ws_size,
                              hipStream_t stream) {
    const float* x  = (const float*)d_in[0];
    const float* w0 = (const float*)d_in[1];
    const float* w1 = (const float*)d_in[2];
    const float* w2 = (const float*)d_in[3];
    const float* w3 = (const float*)d_in[4];
    const float* w4 = (const float*)d_in[5];
    const float* w5 = (const float*)d_in[6];
    const float* w6 = (const float*)d_in[7];

    int8_t* A = (int8_t*)d_ws;
    int8_t* B = A + 58491136;

    // L0: (64,3,256,256) -> signs (64,4,127,s128)
    conv0_pool_sign<<<16129, 256, 0, stream>>>(x, w0, A);

    auto gy = [](int Wo) { return ((Wo + 63) / 64) * ((Wo + 31) / 32); };

    //                 in  w    out   cout  W   WS   Wo  WSo
    conv_dot<4,  4, false><<<dim3(2,  gy(125), 64), 256, 0, stream>>>(A, w1, B,     8,  127, 128, 125, 128);
    conv_dot<8,  4, false><<<dim3(4,  gy(123), 64), 256, 0, stream>>>(B, w2, A,     16, 125, 128, 123, 124);
    conv_dot<16, 4, false><<<dim3(8,  gy(121), 64), 256, 0, stream>>>(A, w3, B,     32, 123, 124, 121, 124);
    conv_dot<32, 4, false><<<dim3(16, gy(119), 64), 256, 0, stream>>>(B, w4, A,     64, 121, 124, 119, 120);
    conv_dot<64, 4, false><<<dim3(8,  gy(117), 64), 256, 0, stream>>>(A, w5, B,     32, 119, 120, 117, 120);
    conv_dot<32, 2, true ><<<dim3(1,  gy(115), 64), 256, 0, stream>>>(B, w6, d_out, 2,  117, 120, 115, 115);
}

// Round 3
// 439.407 us; speedup vs baseline: 17.5135x; 1.7439x over previous
//
#include <hip/hip_runtime.h>
#include <stdint.h>

// Ternary CNN, 7 layers. L0: fp64-exact conv+pool+sign (NCHW). L1-L2: sdot4
// kernels (NCHW in; L2 emits NHWC). L3-L6: implicit-GEMM int8 MFMA in NHWC:
// v_mfma_i32_16x16x64_i8, B-fragment = one aligned dwordx4 per lane straight
// from the NHWC tensor (channels innermost), taps packed into K (64/CIN taps
// per MFMA). Accumulate 9 taps in AGPRs, clamp to [-1,1], store NHWC bytes
// (or float NCHW for the last layer).
//
// Workspace ping-pong:
//  A @ 0        : L0 out NCHW (64,4,127,s128) 4.2MB ; L2 out NHWC (64,123,123,16) 15.5MB ;
//                 L4 out NHWC (64,119,119,64) 58.0MB
//  B @ 58491136 : L1 out NCHW (64,8,125,s128) 8.2MB ; L3 out NHWC (64,121,121,32) 30.0MB ;
//                 L5 out NHWC (64,117,117,32) 28.1MB

#define DEVINL __device__ __forceinline__
typedef int i32x4 __attribute__((ext_vector_type(4)));

DEVINL uint32_t alignb(uint32_t hi, uint32_t lo, int k) {
#if __has_builtin(__builtin_amdgcn_alignbyte)
    return __builtin_amdgcn_alignbyte(hi, lo, (uint32_t)k);
#else
    return (uint32_t)(((((uint64_t)hi) << 32) | (uint64_t)lo) >> (8 * k));
#endif
}

DEVINL int dot4(uint32_t a, uint32_t b, int c) {
#if __has_builtin(__builtin_amdgcn_sdot4)
    return __builtin_amdgcn_sdot4((int)a, (int)b, c, false);
#else
    #pragma unroll
    for (int i = 0; i < 4; ++i)
        c += (int)(int8_t)(a >> (8 * i)) * (int)(int8_t)(b >> (8 * i));
    return c;
#endif
}

// ---------------- Layer 0: conv(raw fp32, sign(w)) -> maxpool2 -> sign -> int8 NCHW s128
__global__ __launch_bounds__(256) void conv0_pool_sign(
    const float* __restrict__ x, const float* __restrict__ w,
    int8_t* __restrict__ out)
{
    __shared__ float ws[108];
    const int t = threadIdx.x;
    if (t < 108) {
        float v = w[t];
        ws[t] = (v > 0.f) ? 1.f : ((v < 0.f) ? -1.f : 0.f);
    }
    __syncthreads();
    const int idx = blockIdx.x * 256 + t;   // 64*4*127*127 = 16129*256
    const int px = idx % 127;
    const int py = (idx / 127) % 127;
    const int co = (idx / (127 * 127)) % 4;
    const int n  = idx / (127 * 127 * 4);

    double a00 = 0.0, a01 = 0.0, a10 = 0.0, a11 = 0.0;
    const float* wsc = &ws[co * 27];
    for (int ci = 0; ci < 3; ++ci) {
        float patch[4][4];
        const float* xp = x + (((size_t)n * 3 + ci) * 256 + 2 * py) * 256 + 2 * px;
        #pragma unroll
        for (int r = 0; r < 4; ++r)
            #pragma unroll
            for (int c = 0; c < 4; ++c)
                patch[r][c] = xp[r * 256 + c];
        #pragma unroll
        for (int ky = 0; ky < 3; ++ky)
            #pragma unroll
            for (int kx = 0; kx < 3; ++kx) {
                const double wv = (double)wsc[ci * 9 + ky * 3 + kx];
                a00 += (double)patch[ky][kx]         * wv;
                a01 += (double)patch[ky][kx + 1]     * wv;
                a10 += (double)patch[ky + 1][kx]     * wv;
                a11 += (double)patch[ky + 1][kx + 1] * wv;
            }
    }
    const double m = fmax(fmax(a00, a01), fmax(a10, a11));
    const size_t o = (((size_t)n * 4 + co) * 127 + py) * 128 + px;
    out[o] = (m > 0.0) ? (int8_t)1 : ((m < 0.0) ? (int8_t)(-1) : (int8_t)0);
}

// ---------------- L1/L2: ternary conv via sdot4 (NCHW in). OUT_NHWC: byte-store NHWC.
template <int CIN, int CO, bool OUT_NHWC>
__global__ __launch_bounds__(256) void conv_dot(
    const int8_t* __restrict__ in, const float* __restrict__ w,
    int8_t* __restrict__ outp, int cout, int W, int WS, int Wo, int WSo)
{
    __shared__ uint32_t pw[CIN * 3 * CO];
    const int t  = threadIdx.x;
    const int cg = blockIdx.x;
    const int n  = blockIdx.z;
    for (int i = t; i < CIN * 3 * CO; i += 256) {
        const int co = i % CO;
        const int r  = i / CO;
        const int ky = r % 3;
        const int ci = r / 3;
        const float* wp = w + (((size_t)(cg * CO + co) * CIN + ci) * 9 + ky * 3);
        uint32_t u = 0;
        #pragma unroll
        for (int k = 0; k < 3; ++k) {
            float v = wp[k];
            int s = (v > 0.f) ? 1 : ((v < 0.f) ? -1 : 0);
            u |= ((uint32_t)(uint8_t)(int8_t)s) << (8 * k);
        }
        pw[i] = u;
    }
    __syncthreads();

    const int tiles_x = (Wo + 63) >> 6;
    const int bx = blockIdx.y % tiles_x;
    const int by = blockIdx.y / tiles_x;
    const int px = bx * 64 + (t & 15) * 4;
    const int py = by * 32 + (t >> 4) * 2;
    if (px >= Wo || py >= Wo) return;

    const size_t ch = (size_t)W * WS;
    const int8_t* p0 = in + (size_t)n * CIN * ch + (size_t)py * WS + px;
    const int r3off = (py + 3 < W) ? 3 * WS : 0;

    int acc[CO][2][4];
    #pragma unroll
    for (int co = 0; co < CO; ++co)
        #pragma unroll
        for (int rr = 0; rr < 2; ++rr)
            #pragma unroll
            for (int j = 0; j < 4; ++j) acc[co][rr][j] = 0;

    #pragma unroll 2
    for (int ci = 0; ci < CIN; ++ci) {
        const int8_t* p = p0 + (size_t)ci * ch;
        uint32_t da[4], db[4];
        {
            const uint32_t* q0 = (const uint32_t*)p;
            const uint32_t* q1 = (const uint32_t*)(p + WS);
            const uint32_t* q2 = (const uint32_t*)(p + 2 * WS);
            const uint32_t* q3 = (const uint32_t*)(p + r3off);
            da[0] = q0[0]; db[0] = q0[1];
            da[1] = q1[0]; db[1] = q1[1];
            da[2] = q2[0]; db[2] = q2[1];
            da[3] = q3[0]; db[3] = q3[1];
        }
        uint32_t wv[3][CO];
        #pragma unroll
        for (int ky = 0; ky < 3; ++ky)
            #pragma unroll
            for (int co = 0; co < CO; ++co)
                wv[ky][co] = pw[(ci * 3 + ky) * CO + co];

        #pragma unroll
        for (int r = 0; r < 4; ++r) {
            uint32_t sw[4];
            sw[0] = da[r];
            sw[1] = alignb(db[r], da[r], 1);
            sw[2] = alignb(db[r], da[r], 2);
            sw[3] = alignb(db[r], da[r], 3);
            #pragma unroll
            for (int co = 0; co < CO; ++co) {
                if (r < 3)
                    #pragma unroll
                    for (int j = 0; j < 4; ++j)
                        acc[co][0][j] = dot4(sw[j], wv[r][co], acc[co][0][j]);
                if (r >= 1)
                    #pragma unroll
                    for (int j = 0; j < 4; ++j)
                        acc[co][1][j] = dot4(sw[j], wv[r - 1][co], acc[co][1][j]);
            }
        }
    }

    #pragma unroll
    for (int co = 0; co < CO; ++co) {
        const int c = cg * CO + co;
        #pragma unroll
        for (int rr = 0; rr < 2; ++rr) {
            const int y = py + rr;
            if (y >= Wo) continue;
            if (OUT_NHWC) {
                int8_t* o = outp + (((size_t)n * Wo + y) * Wo + px) * cout + c;
                #pragma unroll
                for (int j = 0; j < 4; ++j)
                    if (px + j < Wo) {
                        int a = acc[co][rr][j];
                        a = a > 1 ? 1 : (a < -1 ? -1 : a);
                        o[(size_t)j * cout] = (int8_t)a;
                    }
            } else {
                int8_t* o = outp + ((size_t)n * cout + c) * ((size_t)Wo * WSo)
                          + (size_t)y * WSo + px;
                if (px + 4 <= Wo) {
                    uint32_t u = 0;
                    #pragma unroll
                    for (int j = 0; j < 4; ++j) {
                        int a = acc[co][rr][j];
                        a = a > 1 ? 1 : (a < -1 ? -1 : a);
                        u |= ((uint32_t)(uint8_t)(int8_t)a) << (8 * j);
                    }
                    *(uint32_t*)o = u;
                } else {
                    #pragma unroll
                    for (int j = 0; j < 4; ++j)
                        if (px + j < Wo) {
                            int a = acc[co][rr][j];
                            a = a > 1 ? 1 : (a < -1 ? -1 : a);
                            o[j] = (int8_t)a;
                        }
                }
            }
        }
    }
}

// ---------------- L3..L6: implicit-GEMM MFMA conv, NHWC int8.
// v_mfma_i32_16x16x64_i8: A lane l: m=l&15, k=(l>>4)*16+j ; B: n=l&15, same k ;
// D: n=l&15, m=(l>>4)*4+reg. K packs TP=64/CIN taps of cin channels.
// Block = 4 waves = 4 consecutive output rows; each wave: 16*MTILES couts x
// full row in 16-pixel fragments (last fragment overlaps — duplicate writes
// of identical values are benign).
template <int CIN, int COUT, int MTILES, bool FOUT>
__global__ __launch_bounds__(256) void conv_mfma(
    const int8_t* __restrict__ in, const float* __restrict__ w,
    void* __restrict__ outp, int Wi, int Wo)
{
    constexpr int TP  = 64 / CIN;            // taps per MFMA
    constexpr int NMF = (9 + TP - 1) / TP;   // MFMAs per K-accumulation
    __shared__ int8_t aw[MTILES * NMF * 1024];

    const int t  = threadIdx.x;
    const int cg = blockIdx.x;
    const int n  = blockIdx.z;

    // Build sign-packed A fragments in LDS (layout = exact lane order).
    for (int idx = t; idx < MTILES * NMF * 1024; idx += 256) {
        const int mt  = idx / (NMF * 1024);
        const int rem = idx % (NMF * 1024);
        const int f   = rem >> 10;
        const int l   = (rem >> 4) & 63;
        const int j   = rem & 15;
        const int m   = l & 15;
        const int g   = l >> 4;
        const int k   = g * 16 + j;
        const int tap = f * TP + k / CIN;
        const int ci  = k % CIN;
        const int co  = cg * (16 * MTILES) + mt * 16 + m;
        int8_t s = 0;
        if (tap < 9 && co < COUT) {
            float v = w[((size_t)co * CIN + ci) * 9 + tap];
            s = (v > 0.f) ? (int8_t)1 : ((v < 0.f) ? (int8_t)(-1) : (int8_t)0);
        }
        aw[idx] = s;
    }
    __syncthreads();

    const int wv = t >> 6;
    const int l  = t & 63;
    const int g  = l >> 4;
    const int npix = l & 15;
    const int y = blockIdx.y * 4 + wv;
    if (y >= Wo) return;

    i32x4 a[MTILES][NMF];
    #pragma unroll
    for (int mt = 0; mt < MTILES; ++mt)
        #pragma unroll
        for (int f = 0; f < NMF; ++f)
            a[mt][f] = *(const i32x4*)&aw[((mt * NMF + f) << 10) + (l << 4)];

    // Per-lane tap byte-offsets into the NHWC input.
    int boff[NMF];
    const int gdiv = (g * 16) / CIN;
    const int coff = (g * 16) % CIN;
    #pragma unroll
    for (int f = 0; f < NMF; ++f) {
        int tap = f * TP + gdiv;
        if (tap > 8) tap = 8;  // A is zero there; any in-bounds address works
        boff[f] = ((tap / 3) * Wi + (tap % 3)) * CIN + coff;
    }

    const int8_t* rowlane = in + (size_t)n * Wi * Wi * CIN
                          + (size_t)y * Wi * CIN + npix * CIN;
    const int nf = (Wo + 15) >> 4;

    for (int i = 0; i < nf; ++i) {
        int x0 = i * 16;
        if (x0 > Wo - 16) x0 = Wo - 16;
        const int8_t* p = rowlane + (size_t)x0 * CIN;

        i32x4 bv[NMF];
        #pragma unroll
        for (int f = 0; f < NMF; ++f)
            bv[f] = *(const i32x4*)(p + boff[f]);

        i32x4 acc[MTILES];
        #pragma unroll
        for (int mt = 0; mt < MTILES; ++mt) {
            acc[mt] = (i32x4){0, 0, 0, 0};
            #pragma unroll
            for (int f = 0; f < NMF; ++f)
                acc[mt] = __builtin_amdgcn_mfma_i32_16x16x64_i8(a[mt][f], bv[f], acc[mt], 0, 0, 0);
        }

        if (!FOUT) {
            uint8_t* orow = (uint8_t*)outp + ((size_t)n * Wo + y) * (size_t)Wo * COUT
                          + (size_t)(x0 + npix) * COUT + cg * (16 * MTILES) + (g << 2);
            #pragma unroll
            for (int mt = 0; mt < MTILES; ++mt) {
                uint32_t u = 0;
                #pragma unroll
                for (int r = 0; r < 4; ++r) {
                    int v = acc[mt][r];
                    v = v > 1 ? 1 : (v < -1 ? -1 : v);
                    u |= ((uint32_t)(uint8_t)(int8_t)v) << (8 * r);
                }
                *(uint32_t*)(orow + mt * 16) = u;
            }
        } else {
            float* fo = (float*)outp;
            #pragma unroll
            for (int r = 0; r < 4; ++r) {
                const int m = g * 4 + r;
                if (m < COUT) {
                    int v = acc[0][r];
                    v = v > 1 ? 1 : (v < -1 ? -1 : v);
                    fo[((size_t)(n * COUT + m) * Wo + y) * Wo + x0 + npix] = (float)v;
                }
            }
        }
    }
}

extern "C" void kernel_launch(void* const* d_in, const int* in_sizes, int n_in,
                              void* d_out, int out_size, void* d_ws, size_t ws_size,
                              hipStream_t stream) {
    const float* x  = (const float*)d_in[0];
    const float* w0 = (const float*)d_in[1];
    const float* w1 = (const float*)d_in[2];
    const float* w2 = (const float*)d_in[3];
    const float* w3 = (const float*)d_in[4];
    const float* w4 = (const float*)d_in[5];
    const float* w5 = (const float*)d_in[6];
    const float* w6 = (const float*)d_in[7];

    int8_t* A = (int8_t*)d_ws;
    int8_t* B = A + 58491136;

    // L0: (64,3,256,256) fp32 -> signs NCHW (64,4,127,s128)
    conv0_pool_sign<<<16129, 256, 0, stream>>>(x, w0, A);

    auto gy = [](int Wo) { return ((Wo + 63) / 64) * ((Wo + 31) / 32); };

    // L1: 4->8, NCHW s128 -> NCHW s128, 127 -> 125
    conv_dot<4, 4, false><<<dim3(2, gy(125), 64), 256, 0, stream>>>(A, w1, B, 8, 127, 128, 125, 128);
    // L2: 8->16, NCHW s128 -> NHWC, 125 -> 123
    conv_dot<8, 4, true ><<<dim3(4, gy(123), 64), 256, 0, stream>>>(B, w2, A, 16, 125, 128, 123, 0);

    // L3: 16->32, NHWC, 123 -> 121.  TP=4, 3 MFMAs/accum, MTILES=2 -> grid.x=1
    conv_mfma<16, 32, 2, false><<<dim3(1, (121 + 3) / 4, 64), 256, 0, stream>>>(A, w3, B, 123, 121);
    // L4: 32->64, NHWC, 121 -> 119.  TP=2, 5 MFMAs, MTILES=2 -> grid.x=2
    conv_mfma<32, 64, 2, false><<<dim3(2, (119 + 3) / 4, 64), 256, 0, stream>>>(B, w4, A, 121, 119);
    // L5: 64->32, NHWC, 119 -> 117.  TP=1, 9 MFMAs, MTILES=2 -> grid.x=1
    conv_mfma<64, 32, 2, false><<<dim3(1, (117 + 3) / 4, 64), 256, 0, stream>>>(A, w5, B, 119, 117);
    // L6: 32->2, NHWC -> float NCHW d_out, 117 -> 115.  MTILES=1
    conv_mfma<32, 2, 1, true ><<<dim3(1, (115 + 3) / 4, 64), 256, 0, stream>>>(B, w6, d_out, 117, 115);
}